// Round 8
// baseline (571.546 us; speedup 1.0000x reference)
//
#include <hip/hip_runtime.h>

typedef unsigned short u16;
typedef unsigned int u32;

using bf16x8 = __attribute__((ext_vector_type(8))) __bf16;
using f32x4  = __attribute__((ext_vector_type(4))) float;
using u16x8  = __attribute__((ext_vector_type(8))) u16;

#define BB 4
#define TT 4096
#define DD 2048
#define MM 16384
#define KK 2048
#define NCHUNK 16
#define CLEN 256

__device__ __forceinline__ u16 f2bf(float f) {
    u32 u = __float_as_uint(f);
    u32 r = (u + 0x7FFFu + ((u >> 16) & 1u)) >> 16;
    return (u16)r;
}

__device__ __forceinline__ void gload_lds16(const void* g, void* l) {
    __builtin_amdgcn_global_load_lds(
        (const __attribute__((address_space(1))) void*)g,
        (__attribute__((address_space(3))) void*)l, 16, 0, 0);
}

// ---------------- fp32 -> bf16 convert (8 elems/thread) ----------------
__global__ __launch_bounds__(256) void cvt_kernel(const float* __restrict__ in,
                                                  u16* __restrict__ out, int n8) {
    int i = blockIdx.x * 256 + threadIdx.x;
    if (i >= n8) return;
    const f32x4* p = (const f32x4*)in + (size_t)i * 2;
    f32x4 a = p[0], b = p[1];
    u16x8 o;
    o[0] = f2bf(a[0]); o[1] = f2bf(a[1]); o[2] = f2bf(a[2]); o[3] = f2bf(a[3]);
    o[4] = f2bf(b[0]); o[5] = f2bf(b[1]); o[6] = f2bf(b[2]); o[7] = f2bf(b[3]);
    *((u16x8*)out + i) = o;
}

// ---------------- fused dual GEMM, balanced 4-phase pipeline ----------------
// Tile 256(M) x 128(e), BK=64, 8 waves (2M x 4N), 2-deep LDS ring (128 KB).
// Phases/K-tile: reads {4,8,8,4}; every MFMA burst consumes frags read >=1
// phase earlier (counted lgkmcnt = this-phase count); stages staggered one
// half-group per phase; vmcnt(2)/vmcnt(4), never 0 in steady state.
#define BMg 256
#define BNg 128
#define BKt 64
#define NTt (KK / BKt)   // 32 K-tiles

#define MF(a_, b_, c_) __builtin_amdgcn_mfma_f32_16x16x32_bf16(a_, b_, c_, 0, 0, 0)

__global__ __launch_bounds__(512, 2) void gemm_dual_p4(
    const u16* __restrict__ xb, const u16* __restrict__ wib, const u16* __restrict__ wgb,
    const float* __restrict__ b_in, const float* __restrict__ b_gate,
    const float* __restrict__ lam, u32* __restrict__ pair)
{
    __shared__ u16 As[2][BMg * BKt];   // 2 x 32 KB
    __shared__ u16 Bi[2][BNg * BKt];   // 2 x 16 KB
    __shared__ u16 Bg[2][BNg * BKt];   // 2 x 16 KB   (total 128 KB)

    const int tid = threadIdx.x;
    const int bid = blockIdx.x;
    const int cpx = gridDim.x >> 3;               // 1024/8 -> bijective
    const int swz = (bid & 7) * cpx + (bid >> 3);
    const int et = swz & 15;
    const int mt = swz >> 4;
    const size_t m0 = (size_t)mt * BMg;
    const size_t e0 = (size_t)et * BNg;

    const int lane = tid & 63;
    const int w = tid >> 6;
    const int wr = w >> 2;        // 0..1 -> m offset wr*128
    const int wc = w & 3;         // 0..3 -> e offset wc*32
    const int r15 = lane & 15;
    const int s4 = lane >> 4;

    // ---- staging maps: per 16KB group, wave w gload j covers LDS chunks
    //      L = w*128 + j*64 + lane; row = L>>3, chunk' = L&7,
    //      src chunk = chunk' ^ (row&7) (XOR swizzle, LDS dest linear).
    const u16 *gSA0[2], *gSA1[2], *gSBI[2], *gSBG[2];
#pragma unroll
    for (int j = 0; j < 2; j++) {
        int L = w * 128 + j * 64 + lane;
        int row = L >> 3;
        int sc = (L & 7) ^ (row & 7);
        gSA0[j] = xb  + (m0 + row) * (size_t)KK + sc * 8;
        gSA1[j] = xb  + (m0 + 128 + row) * (size_t)KK + sc * 8;
        gSBI[j] = wib + (e0 + row) * (size_t)KK + sc * 8;
        gSBG[j] = wgb + (e0 + row) * (size_t)KK + sc * 8;
    }
    const int dstE = (w * 128 + lane) * 8;   // + j*512; SA1 adds 8192

#define ST_A0(t) do { int _b = ((t) & 1); size_t _k = (size_t)(t) * BKt; \
        gload_lds16(gSA0[0] + _k, &As[_b][dstE]); \
        gload_lds16(gSA0[1] + _k, &As[_b][dstE + 512]); } while (0)
#define ST_A1(t) do { int _b = ((t) & 1); size_t _k = (size_t)(t) * BKt; \
        gload_lds16(gSA1[0] + _k, &As[_b][8192 + dstE]); \
        gload_lds16(gSA1[1] + _k, &As[_b][8192 + dstE + 512]); } while (0)
#define ST_BI(t) do { int _b = ((t) & 1); size_t _k = (size_t)(t) * BKt; \
        gload_lds16(gSBI[0] + _k, &Bi[_b][dstE]); \
        gload_lds16(gSBI[1] + _k, &Bi[_b][dstE + 512]); } while (0)
#define ST_BG(t) do { int _b = ((t) & 1); size_t _k = (size_t)(t) * BKt; \
        gload_lds16(gSBG[0] + _k, &Bg[_b][dstE]); \
        gload_lds16(gSBG[1] + _k, &Bg[_b][dstE + 512]); } while (0)

    // ---- read offsets (elements): row*64 + swizzled chunk
    int cE[2];
#pragma unroll
    for (int ks = 0; ks < 2; ks++) cE[ks] = ((((ks << 2) | s4) ^ (r15 & 7)) << 3);
    int aR[8], bR[2];
#pragma unroll
    for (int mF = 0; mF < 8; mF++) aR[mF] = (wr * 128 + mF * 16 + r15) << 6;
#pragma unroll
    for (int ni = 0; ni < 2; ni++) bR[ni] = (wc * 32 + ni * 16 + r15) << 6;

#define RD_A(b_, mF_, ks_)  (*(const bf16x8*)&As[b_][aR[mF_] + cE[ks_]])
#define RD_BI(b_, ni_, ks_) (*(const bf16x8*)&Bi[b_][bR[ni_] + cE[ks_]])
#define RD_BG(b_, ni_, ks_) (*(const bf16x8*)&Bg[b_][bR[ni_] + cE[ks_]])

    f32x4 accI[8][2], accG[8][2];
#pragma unroll
    for (int i = 0; i < 8; i++)
#pragma unroll
        for (int j = 0; j < 2; j++) {
            accI[i][j] = (f32x4){0.f, 0.f, 0.f, 0.f};
            accG[i][j] = (f32x4){0.f, 0.f, 0.f, 0.f};
        }

    bf16x8 aA[4], aB[4], aC[4], aD[4];   // aC/aD: carried ks1 frags
    bf16x8 b0v[4], b1v[4];               // {BIn0,BIn1,BGn0,BGn1} ks0 / ks1(carried)

#define LGKM(n) do { asm volatile("s_waitcnt lgkmcnt(" #n ")" ::: "memory"); \
                     __builtin_amdgcn_sched_barrier(0); } while (0)
#define VMC(n)  asm volatile("s_waitcnt vmcnt(" #n ")" ::: "memory")
#define BARx()  __builtin_amdgcn_s_barrier()
// 16 MFMA: 4 m-frags x {BI n0, BI n1, BG n0, BG n1}
#define BURST(aV, bV, base) do { __builtin_amdgcn_s_setprio(1); \
        _Pragma("unroll") for (int m = 0; m < 4; m++) { \
            accI[m + (base)][0] = MF(aV[m], bV[0], accI[m + (base)][0]); \
            accI[m + (base)][1] = MF(aV[m], bV[1], accI[m + (base)][1]); \
            accG[m + (base)][0] = MF(aV[m], bV[2], accG[m + (base)][0]); \
            accG[m + (base)][1] = MF(aV[m], bV[3], accG[m + (base)][1]); } \
        __builtin_amdgcn_s_setprio(0); } while (0)

    // ---- prologue: stage tiles 0 and 1 (16 gloads), drain tile 0
    ST_A0(0); ST_A1(0); ST_BI(0); ST_BG(0);
    ST_A0(1); ST_A1(1); ST_BI(1); ST_BG(1);
    VMC(8);
    BARx();

    // ---- tile 0 peel (buf 0, no stages, bursts Q0,Q1 only)
    {
#pragma unroll
        for (int m = 0; m < 4; m++) aA[m] = RD_A(0, m, 0);
#pragma unroll
        for (int n = 0; n < 2; n++) { b0v[n] = RD_BI(0, n, 0); b0v[2 + n] = RD_BG(0, n, 0); }
#pragma unroll
        for (int m = 0; m < 4; m++) aB[m] = RD_A(0, m + 4, 0);
#pragma unroll
        for (int m = 0; m < 4; m++) aC[m] = RD_A(0, m, 1);
#pragma unroll
        for (int n = 0; n < 2; n++) { b1v[n] = RD_BI(0, n, 1); b1v[2 + n] = RD_BG(0, n, 1); }
        BARx();
        LGKM(8);                       // aA,b0v,aB drained
        BURST(aA, b0v, 0);             // Q0(0)
#pragma unroll
        for (int m = 0; m < 4; m++) aD[m] = RD_A(0, m + 4, 1);
        BARx();
        LGKM(4);                       // aC,b1v drained
        BURST(aB, b0v, 4);             // Q1(0)
        VMC(4);                        // SA0,SA1(1) drained; SBI,SBG(1) in flight
        BARx();
    }

    // ---- steady tiles 1..30
#pragma unroll 2
    for (int t = 1; t < NTt - 1; ++t) {
        const int b = t & 1;
        // ph0: read aA(t); stage SA0(t+1); burst Q2(t-1)
#pragma unroll
        for (int m = 0; m < 4; m++) aA[m] = RD_A(b, m, 0);
        ST_A0(t + 1);
        BARx();
        LGKM(4);
        BURST(aC, b1v, 0);
        VMC(2);                        // SBI,SBG(t) drained for ph1's b0v
        BARx();
        // ph1: read b0v(t), aB(t); stage SA1(t+1); burst Q3(t-1)
#pragma unroll
        for (int n = 0; n < 2; n++) { b0v[n] = RD_BI(b, n, 0); b0v[2 + n] = RD_BG(b, n, 0); }
#pragma unroll
        for (int m = 0; m < 4; m++) aB[m] = RD_A(b, m + 4, 0);
        ST_A1(t + 1);
        BARx();
        LGKM(8);
        BURST(aD, b1v, 4);
        BARx();
        // ph2: read aC(t), b1v(t); stage SBI(t+1); burst Q0(t)
#pragma unroll
        for (int m = 0; m < 4; m++) aC[m] = RD_A(b, m, 1);
#pragma unroll
        for (int n = 0; n < 2; n++) { b1v[n] = RD_BI(b, n, 1); b1v[2 + n] = RD_BG(b, n, 1); }
        ST_BI(t + 1);
        BARx();
        LGKM(8);
        BURST(aA, b0v, 0);
        BARx();
        // ph3: read aD(t); stage SBG(t+1); burst Q1(t)
#pragma unroll
        for (int m = 0; m < 4; m++) aD[m] = RD_A(b, m + 4, 1);
        ST_BG(t + 1);
        BARx();
        LGKM(4);
        BURST(aB, b0v, 4);
        VMC(4);                        // SA0,SA1(t+1) drained for next ph0
        BARx();
    }

    // ---- tile 31 peel (buf 1, no stages)
    {
#pragma unroll
        for (int m = 0; m < 4; m++) aA[m] = RD_A(1, m, 0);
        BARx();
        LGKM(4);
        BURST(aC, b1v, 0);             // Q2(30)
        VMC(0);
        BARx();
#pragma unroll
        for (int n = 0; n < 2; n++) { b0v[n] = RD_BI(1, n, 0); b0v[2 + n] = RD_BG(1, n, 0); }
#pragma unroll
        for (int m = 0; m < 4; m++) aB[m] = RD_A(1, m + 4, 0);
        BARx();
        LGKM(8);
        BURST(aD, b1v, 4);             // Q3(30)
        BARx();
#pragma unroll
        for (int m = 0; m < 4; m++) aC[m] = RD_A(1, m, 1);
#pragma unroll
        for (int n = 0; n < 2; n++) { b1v[n] = RD_BI(1, n, 1); b1v[2 + n] = RD_BG(1, n, 1); }
        BARx();
        LGKM(8);
        BURST(aA, b0v, 0);             // Q0(31)
        BARx();
#pragma unroll
        for (int m = 0; m < 4; m++) aD[m] = RD_A(1, m + 4, 1);
        BARx();
        LGKM(4);
        BURST(aB, b0v, 4);             // Q1(31)
        LGKM(0);
        BURST(aC, b1v, 0);             // Q2(31)
        BURST(aD, b1v, 4);             // Q3(31)
    }

    // ---- epilogue ----
    float spl[2], biv[2], bgv[2];
    size_t ecol[2];
#pragma unroll
    for (int ni = 0; ni < 2; ni++) {
        size_t e = e0 + wc * 32 + ni * 16 + r15;
        ecol[ni] = e;
        spl[ni] = 8.0f * log1pf(__expf(lam[e]));
        biv[ni] = b_in[e];
        bgv[ni] = b_gate[e];
    }
    const int rbase = s4 * 4;
#pragma unroll
    for (int mi = 0; mi < 8; mi++) {
#pragma unroll
        for (int r = 0; r < 4; r++) {
            size_t m = m0 + wr * 128 + mi * 16 + rbase + r;
#pragma unroll
            for (int ni = 0; ni < 2; ni++) {
                size_t e = ecol[ni];
                float ig = accI[mi][ni][r] + biv[ni];
                float rg = accG[mi][ni][r] + bgv[ni];
                float sigr = 1.f / (1.f + __expf(-rg));
                float g = spl[ni] * sigr;
                float beta = sqrtf(1.f - __expf(-2.f * g) + 1e-6f);
                float xv = __uint_as_float((u32)xb[m * KK + e] << 16);  // L2-hot bf16 x
                float xbeta = beta * (1.f / (1.f + __expf(-ig))) * xv;
                u32 pk = (u32)f2bf(g) | (((u32)f2bf(xbeta)) << 16);
                pair[m * DD + e] = pk;
            }
        }
    }
#undef ST_A0
#undef ST_A1
#undef ST_BI
#undef ST_BG
#undef RD_A
#undef RD_BI
#undef RD_BG
#undef BURST
}

// ---------------- chunked scan ----------------
// pair layout [B,T,D]: low16 = bf16(g), high16 = bf16(xbeta); alpha = exp(-g)
__global__ __launch_bounds__(256) void scanA(const u32* __restrict__ pair,
                                             float* __restrict__ aggG,
                                             float* __restrict__ aggB) {
    int gid = blockIdx.x * 256 + threadIdx.x;   // 131072
    int e = gid & (DD - 1);
    int rest = gid >> 11;     // 0..63
    int b = rest & 3;
    int c = rest >> 2;        // 0..15
    const u32* p = pair + ((size_t)(b * TT + c * CLEN)) * DD + e;
    float gsum = 0.f, h = 0.f;
#pragma unroll 4
    for (int t = 0; t < CLEN; ++t) {
        u32 v = *p; p += DD;
        float gf = __uint_as_float(v << 16);
        float xbv = __uint_as_float(v & 0xFFFF0000u);
        gsum += gf;
        h = fmaf(__expf(-gf), h, xbv);
    }
    int idx = ((b * NCHUNK + c) << 11) | e;
    aggG[idx] = gsum;
    aggB[idx] = h;
}

__global__ __launch_bounds__(256) void scanB(const float* __restrict__ aggG,
                                             const float* __restrict__ aggB,
                                             float* __restrict__ carry) {
    int gid = blockIdx.x * 256 + threadIdx.x;   // 8192
    int e = gid & (DD - 1);
    int b = gid >> 11;
    float h = 0.f;
#pragma unroll
    for (int c = 0; c < NCHUNK; ++c) {
        int idx = ((b * NCHUNK + c) << 11) | e;
        carry[idx] = h;
        h = fmaf(__expf(-aggG[idx]), h, aggB[idx]);
    }
}

__global__ __launch_bounds__(256) void scanC(const u32* __restrict__ pair,
                                             const float* __restrict__ carry,
                                             float* __restrict__ out) {
    int gid = blockIdx.x * 256 + threadIdx.x;   // 131072
    int e = gid & (DD - 1);
    int rest = gid >> 11;
    int b = rest & 3;
    int c = rest >> 2;
    const u32* p = pair + ((size_t)(b * TT + c * CLEN)) * DD + e;
    float* o = out + ((size_t)(b * TT + c * CLEN)) * DD + e;
    float h = carry[((b * NCHUNK + c) << 11) | e];
#pragma unroll 4
    for (int t = 0; t < CLEN; ++t) {
        u32 v = *p; p += DD;
        float gf = __uint_as_float(v << 16);
        float xbv = __uint_as_float(v & 0xFFFF0000u);
        h = fmaf(__expf(-gf), h, xbv);
        *o = h; o += DD;
    }
}

extern "C" void kernel_launch(void* const* d_in, const int* in_sizes, int n_in,
                              void* d_out, int out_size, void* d_ws, size_t ws_size,
                              hipStream_t stream) {
    const float* x      = (const float*)d_in[0];
    const float* W_in   = (const float*)d_in[1];
    const float* b_in   = (const float*)d_in[2];
    const float* W_gate = (const float*)d_in[3];
    const float* b_gate = (const float*)d_in[4];
    const float* lam    = (const float*)d_in[5];
    float* out = (float*)d_out;

    char* ws = (char*)d_ws;
    u16* xb   = (u16*)(ws);                  // 67,108,864 B
    u16* wib  = (u16*)(ws + 67108864);       //  8,388,608 B
    u16* wgb  = (u16*)(ws + 75497472);       //  8,388,608 B
    u32* pair = (u32*)(ws + 83886080);       // 134,217,728 B
    float* aggG  = (float*)(ws + 218103808); // 524,288 B
    float* aggB  = (float*)(ws + 218628096); // 524,288 B
    float* carry = (float*)(ws + 219152384); // 524,288 B

    cvt_kernel<<<16384, 256, 0, stream>>>(x, xb, MM * KK / 8);
    cvt_kernel<<<2048, 256, 0, stream>>>(W_in, wib, DD * KK / 8);
    cvt_kernel<<<2048, 256, 0, stream>>>(W_gate, wgb, DD * KK / 8);
    gemm_dual_p4<<<(MM / BMg) * (DD / BNg), 512, 0, stream>>>(xb, wib, wgb, b_in, b_gate, lam, pair);
    scanA<<<BB * DD * NCHUNK / 256, 256, 0, stream>>>(pair, aggG, aggB);
    scanB<<<BB * DD / 256, 256, 0, stream>>>(aggG, aggB, carry);
    scanC<<<BB * DD * NCHUNK / 256, 256, 0, stream>>>(pair, carry, out);
}

// Round 9
// 472.848 us; speedup vs baseline: 1.2087x; 1.2087x over previous
//
#include <hip/hip_runtime.h>

typedef unsigned short u16;
typedef unsigned int u32;

using bf16x8 = __attribute__((ext_vector_type(8))) __bf16;
using f32x4  = __attribute__((ext_vector_type(4))) float;
using u16x8  = __attribute__((ext_vector_type(8))) u16;

#define BB 4
#define TT 4096
#define DD 2048
#define MM 16384
#define KK 2048
#define NCHUNK 16
#define CLEN 256

__device__ __forceinline__ u16 f2bf(float f) {
    u32 u = __float_as_uint(f);
    u32 r = (u + 0x7FFFu + ((u >> 16) & 1u)) >> 16;
    return (u16)r;
}

__device__ __forceinline__ void gload_lds16(const void* g, void* l) {
    __builtin_amdgcn_global_load_lds(
        (const __attribute__((address_space(1))) void*)g,
        (__attribute__((address_space(3))) void*)l, 16, 0, 0);
}

// ---------------- fp32 -> bf16 convert (8 elems/thread) ----------------
__global__ __launch_bounds__(256) void cvt_kernel(const float* __restrict__ in,
                                                  u16* __restrict__ out, int n8) {
    int i = blockIdx.x * 256 + threadIdx.x;
    if (i >= n8) return;
    const f32x4* p = (const f32x4*)in + (size_t)i * 2;
    f32x4 a = p[0], b = p[1];
    u16x8 o;
    o[0] = f2bf(a[0]); o[1] = f2bf(a[1]); o[2] = f2bf(a[2]); o[3] = f2bf(a[3]);
    o[4] = f2bf(b[0]); o[5] = f2bf(b[1]); o[6] = f2bf(b[2]); o[7] = f2bf(b[3]);
    *((u16x8*)out + i) = o;
}

// ---------------- fused dual GEMM, m201-lockstep 2-phase + gate epilogue ----------------
// Tile 256(M) x 128(e), BK=32, 8 waves (2M x 4N), 4-deep LDS rings (128 KB).
// Phase = {reads, stage, barrier, lgkm(0), 16 MFMA, barrier}; reads {8,4};
// stage distance 2 K-steps; vmcnt(4) per step end (0 only at t=NT-2).
#define BMg 256
#define BNg 128
#define BKg 32
#define NT (KK / BKg)   // 64 K-steps

#define MF(a_, b_, c_) __builtin_amdgcn_mfma_f32_16x16x32_bf16(a_, b_, c_, 0, 0, 0)

__global__ __launch_bounds__(512, 2) void gemm_lock2(
    const u16* __restrict__ xb, const u16* __restrict__ wib, const u16* __restrict__ wgb,
    const float* __restrict__ b_in, const float* __restrict__ b_gate,
    const float* __restrict__ lam, u32* __restrict__ pair)
{
    __shared__ u16 As[4][BMg * BKg];   // 4 x 16 KB
    __shared__ u16 Bi[4][BNg * BKg];   // 4 x 8 KB
    __shared__ u16 Bg[4][BNg * BKg];   // 4 x 8 KB   (total 128 KB)

    const int tid = threadIdx.x;
    const int bid = blockIdx.x;
    const int cpx = gridDim.x >> 3;               // 1024/8 -> bijective
    const int swz = (bid & 7) * cpx + (bid >> 3);
    const int et = swz & 15;
    const int mt = swz >> 4;
    const size_t m0 = (size_t)mt * BMg;
    const size_t e0 = (size_t)et * BNg;

    const int lane = tid & 63;
    const int w = tid >> 6;
    const int wr = w >> 2;        // 0..1 -> m offset wr*128
    const int wc = w & 3;         // 0..3 -> e offset wc*32
    const int r15 = lane & 15;
    const int s4 = lane >> 4;

    // ---- staging maps. A(t)=16KB=2 gloads: chunk L=j*512+tid -> row L>>2,
    //      chunk L&3; global chunk = (L&3) ^ (row&3) ^ ((row>>2)&3).
    //      Bi/Bg(t)=8KB=1 gload each: L=tid.
    const u16 *gA[2], *gBi, *gBg;
#pragma unroll
    for (int j = 0; j < 2; j++) {
        int L = j * 512 + tid;
        int row = L >> 2;
        int cs = (L & 3) ^ (row & 3) ^ ((row >> 2) & 3);
        gA[j] = xb + (m0 + row) * (size_t)KK + cs * 8;
    }
    {
        int row = tid >> 2;
        int cs = (tid & 3) ^ (row & 3) ^ ((row >> 2) & 3);
        gBi = wib + (e0 + row) * (size_t)KK + cs * 8;
        gBg = wgb + (e0 + row) * (size_t)KK + cs * 8;
    }

#define ST_A(t) do { int _s = (t) & 3; size_t _k = (size_t)(t) * BKg; \
        gload_lds16(gA[0] + _k, &As[_s][tid * 8]); \
        gload_lds16(gA[1] + _k, &As[_s][4096 + tid * 8]); } while (0)
#define ST_B(t) do { int _s = (t) & 3; size_t _k = (size_t)(t) * BKg; \
        gload_lds16(gBi + _k, &Bi[_s][tid * 8]); \
        gload_lds16(gBg + _k, &Bg[_s][tid * 8]); } while (0)

    // ---- read offsets (elements): row*32 + swizzled chunk (lane-uniform XOR)
    const int csw = (s4 ^ (r15 & 3) ^ ((r15 >> 2) & 3)) << 3;
    int aR[8], bR[2];
#pragma unroll
    for (int mF = 0; mF < 8; mF++) aR[mF] = ((wr * 128 + mF * 16 + r15) << 5) + csw;
#pragma unroll
    for (int ni = 0; ni < 2; ni++) bR[ni] = ((wc * 32 + ni * 16 + r15) << 5) + csw;

    f32x4 accI[8][2], accG[8][2];
#pragma unroll
    for (int i = 0; i < 8; i++)
#pragma unroll
        for (int j = 0; j < 2; j++) {
            accI[i][j] = (f32x4){0.f, 0.f, 0.f, 0.f};
            accG[i][j] = (f32x4){0.f, 0.f, 0.f, 0.f};
        }

    bf16x8 aF[4], bv[4];   // bv = {bI0, bI1, bG0, bG1}

#define LGKM0() do { asm volatile("s_waitcnt lgkmcnt(0)" ::: "memory"); \
                     __builtin_amdgcn_sched_barrier(0); } while (0)
#define BURST(base) do { __builtin_amdgcn_s_setprio(1); \
        _Pragma("unroll") for (int m = 0; m < 4; m++) { \
            accI[m + (base)][0] = MF(aF[m], bv[0], accI[m + (base)][0]); \
            accI[m + (base)][1] = MF(aF[m], bv[1], accI[m + (base)][1]); \
            accG[m + (base)][0] = MF(aF[m], bv[2], accG[m + (base)][0]); \
            accG[m + (base)][1] = MF(aF[m], bv[3], accG[m + (base)][1]); } \
        __builtin_amdgcn_s_setprio(0); } while (0)

    // ---- prologue: stage steps 0,1; drain step 0 (leave step 1 in flight)
    ST_A(0); ST_B(0);
    ST_A(1); ST_B(1);
    asm volatile("s_waitcnt vmcnt(4)" ::: "memory");
    __builtin_amdgcn_s_barrier();

#pragma unroll 4
    for (int t = 0; t < NT; ++t) {
        const int s = t & 3;
        // ---- phase 0: 8 reads (A[0-3], all B) + stage A(t+2); burst Q0
#pragma unroll
        for (int m = 0; m < 4; m++) aF[m] = *(const bf16x8*)&As[s][aR[m]];
        bv[0] = *(const bf16x8*)&Bi[s][bR[0]];
        bv[1] = *(const bf16x8*)&Bi[s][bR[1]];
        bv[2] = *(const bf16x8*)&Bg[s][bR[0]];
        bv[3] = *(const bf16x8*)&Bg[s][bR[1]];
        if (t < NT - 2) ST_A(t + 2);
        __builtin_amdgcn_s_barrier();
        LGKM0();
        BURST(0);
        __builtin_amdgcn_s_barrier();
        // ---- phase 1: 4 reads (A[4-7]) + stage B(t+2); burst Q1
#pragma unroll
        for (int m = 0; m < 4; m++) aF[m] = *(const bf16x8*)&As[s][aR[m + 4]];
        if (t < NT - 2) ST_B(t + 2);
        __builtin_amdgcn_s_barrier();
        LGKM0();
        BURST(4);
        if (t == NT - 3)      asm volatile("s_waitcnt vmcnt(0)" ::: "memory");
        else if (t < NT - 3)  asm volatile("s_waitcnt vmcnt(4)" ::: "memory");
        __builtin_amdgcn_s_barrier();
    }

    // ---- epilogue ----
    float spl[2], biv[2], bgv[2];
    size_t ecol[2];
#pragma unroll
    for (int ni = 0; ni < 2; ni++) {
        size_t e = e0 + wc * 32 + ni * 16 + r15;
        ecol[ni] = e;
        spl[ni] = 8.0f * log1pf(__expf(lam[e]));
        biv[ni] = b_in[e];
        bgv[ni] = b_gate[e];
    }
    const int rbase = s4 * 4;
#pragma unroll
    for (int mi = 0; mi < 8; mi++) {
#pragma unroll
        for (int r = 0; r < 4; r++) {
            size_t m = m0 + wr * 128 + mi * 16 + rbase + r;
#pragma unroll
            for (int ni = 0; ni < 2; ni++) {
                size_t e = ecol[ni];
                float ig = accI[mi][ni][r] + biv[ni];
                float rg = accG[mi][ni][r] + bgv[ni];
                float sigr = 1.f / (1.f + __expf(-rg));
                float g = spl[ni] * sigr;
                float beta = sqrtf(1.f - __expf(-2.f * g) + 1e-6f);
                float xv = __uint_as_float((u32)xb[m * KK + e] << 16);  // L2-hot bf16 x
                float xbeta = beta * (1.f / (1.f + __expf(-ig))) * xv;
                u32 pk = (u32)f2bf(g) | (((u32)f2bf(xbeta)) << 16);
                pair[m * DD + e] = pk;
            }
        }
    }
#undef ST_A
#undef ST_B
#undef BURST
}

// ---------------- chunked scan ----------------
// pair layout [B,T,D]: low16 = bf16(g), high16 = bf16(xbeta); alpha = exp(-g)
__global__ __launch_bounds__(256) void scanA(const u32* __restrict__ pair,
                                             float* __restrict__ aggG,
                                             float* __restrict__ aggB) {
    int gid = blockIdx.x * 256 + threadIdx.x;   // 131072
    int e = gid & (DD - 1);
    int rest = gid >> 11;     // 0..63
    int b = rest & 3;
    int c = rest >> 2;        // 0..15
    const u32* p = pair + ((size_t)(b * TT + c * CLEN)) * DD + e;
    float gsum = 0.f, h = 0.f;
#pragma unroll 4
    for (int t = 0; t < CLEN; ++t) {
        u32 v = *p; p += DD;
        float gf = __uint_as_float(v << 16);
        float xbv = __uint_as_float(v & 0xFFFF0000u);
        gsum += gf;
        h = fmaf(__expf(-gf), h, xbv);
    }
    int idx = ((b * NCHUNK + c) << 11) | e;
    aggG[idx] = gsum;
    aggB[idx] = h;
}

__global__ __launch_bounds__(256) void scanB(const float* __restrict__ aggG,
                                             const float* __restrict__ aggB,
                                             float* __restrict__ carry) {
    int gid = blockIdx.x * 256 + threadIdx.x;   // 8192
    int e = gid & (DD - 1);
    int b = gid >> 11;
    float h = 0.f;
#pragma unroll
    for (int c = 0; c < NCHUNK; ++c) {
        int idx = ((b * NCHUNK + c) << 11) | e;
        carry[idx] = h;
        h = fmaf(__expf(-aggG[idx]), h, aggB[idx]);
    }
}

__global__ __launch_bounds__(256) void scanC(const u32* __restrict__ pair,
                                             const float* __restrict__ carry,
                                             float* __restrict__ out) {
    int gid = blockIdx.x * 256 + threadIdx.x;   // 131072
    int e = gid & (DD - 1);
    int rest = gid >> 11;
    int b = rest & 3;
    int c = rest >> 2;
    const u32* p = pair + ((size_t)(b * TT + c * CLEN)) * DD + e;
    float* o = out + ((size_t)(b * TT + c * CLEN)) * DD + e;
    float h = carry[((b * NCHUNK + c) << 11) | e];
#pragma unroll 4
    for (int t = 0; t < CLEN; ++t) {
        u32 v = *p; p += DD;
        float gf = __uint_as_float(v << 16);
        float xbv = __uint_as_float(v & 0xFFFF0000u);
        h = fmaf(__expf(-gf), h, xbv);
        *o = h; o += DD;
    }
}

extern "C" void kernel_launch(void* const* d_in, const int* in_sizes, int n_in,
                              void* d_out, int out_size, void* d_ws, size_t ws_size,
                              hipStream_t stream) {
    const float* x      = (const float*)d_in[0];
    const float* W_in   = (const float*)d_in[1];
    const float* b_in   = (const float*)d_in[2];
    const float* W_gate = (const float*)d_in[3];
    const float* b_gate = (const float*)d_in[4];
    const float* lam    = (const float*)d_in[5];
    float* out = (float*)d_out;

    char* ws = (char*)d_ws;
    u16* xb   = (u16*)(ws);                  // 67,108,864 B
    u16* wib  = (u16*)(ws + 67108864);       //  8,388,608 B
    u16* wgb  = (u16*)(ws + 75497472);       //  8,388,608 B
    u32* pair = (u32*)(ws + 83886080);       // 134,217,728 B
    float* aggG  = (float*)(ws + 218103808); // 524,288 B
    float* aggB  = (float*)(ws + 218628096); // 524,288 B
    float* carry = (float*)(ws + 219152384); // 524,288 B

    cvt_kernel<<<16384, 256, 0, stream>>>(x, xb, MM * KK / 8);
    cvt_kernel<<<2048, 256, 0, stream>>>(W_in, wib, DD * KK / 8);
    cvt_kernel<<<2048, 256, 0, stream>>>(W_gate, wgb, DD * KK / 8);
    gemm_lock2<<<(MM / BMg) * (DD / BNg), 512, 0, stream>>>(xb, wib, wgb, b_in, b_gate, lam, pair);
    scanA<<<BB * DD * NCHUNK / 256, 256, 0, stream>>>(pair, aggG, aggB);
    scanB<<<BB * DD / 256, 256, 0, stream>>>(aggG, aggB, carry);
    scanC<<<BB * DD * NCHUNK / 256, 256, 0, stream>>>(pair, carry, out);
}